// Round 3
// baseline (3126.169 us; speedup 1.0000x reference)
//
#include <hip/hip_runtime.h>
#include <math.h>

// Problem constants
#define BB 8
#define CC 3
#define DD 24
#define HH 128
#define WW 128
#define HW (HH * WW)
#define OCC 16
#define DOUT 22   // 24 - 2
#define HOUT 126
#define WOUT 126
#define DZH 11    // dz per group (2 groups per block)

// Per-tap 16-wide FMA into 16 named accumulators; weights broadcast from LDS
// as 4x float4 (wave-uniform address -> conflict-free broadcast ds_read_b128).
#define TAP(S, T, XV)                                                          \
  do {                                                                         \
    const float4 wA = *reinterpret_cast<const float4*>(&wlds[((S)*9+(T))*16 + 0]);  \
    const float4 wB = *reinterpret_cast<const float4*>(&wlds[((S)*9+(T))*16 + 4]);  \
    const float4 wC = *reinterpret_cast<const float4*>(&wlds[((S)*9+(T))*16 + 8]);  \
    const float4 wD = *reinterpret_cast<const float4*>(&wlds[((S)*9+(T))*16 + 12]); \
    y0  = fmaf((XV), wA.x, y0);  y1  = fmaf((XV), wA.y, y1);                   \
    y2  = fmaf((XV), wA.z, y2);  y3  = fmaf((XV), wA.w, y3);                   \
    y4  = fmaf((XV), wB.x, y4);  y5  = fmaf((XV), wB.y, y5);                   \
    y6  = fmaf((XV), wB.z, y6);  y7  = fmaf((XV), wB.w, y7);                   \
    y8  = fmaf((XV), wC.x, y8);  y9  = fmaf((XV), wC.y, y9);                   \
    y10 = fmaf((XV), wC.z, y10); y11 = fmaf((XV), wC.w, y11);                  \
    y12 = fmaf((XV), wD.x, y12); y13 = fmaf((XV), wD.y, y13);                  \
    y14 = fmaf((XV), wD.z, y14); y15 = fmaf((XV), wD.w, y15);                  \
  } while (0)

// One (c,kd) input slice: 9 x-values (3x3 patch), 9 taps * 16 oc FMAs.
#define SLICE(S, P)                                                            \
  do {                                                                         \
    const float xv0 = (P)[0];        const float xv1 = (P)[1];                 \
    const float xv2 = (P)[2];        const float xv3 = (P)[WW];                \
    const float xv4 = (P)[WW + 1];   const float xv5 = (P)[WW + 2];            \
    const float xv6 = (P)[2 * WW];   const float xv7 = (P)[2 * WW + 1];        \
    const float xv8 = (P)[2 * WW + 2];                                         \
    TAP(S, 0, xv0); TAP(S, 1, xv1); TAP(S, 2, xv2);                            \
    TAP(S, 3, xv3); TAP(S, 4, xv4); TAP(S, 5, xv5);                            \
    TAP(S, 6, xv6); TAP(S, 7, xv7); TAP(S, 8, xv8);                            \
  } while (0)

__global__ __launch_bounds__(256) void conv_min_softmax_kernel(
    const float* __restrict__ x, const float* __restrict__ wt,
    float* __restrict__ out) {
  __shared__ __align__(16) float wlds[81 * 16];  // [tap][oc]
  __shared__ float sm[WOUT * 17 + 16];           // group-1 partial min, stride 17

  const int tid = threadIdx.x;

  // Stage weights transposed: wlds[tap*16 + oc] = wt[oc*81 + tap]
  for (int i = tid; i < 81 * 16; i += 256) {
    const int tap = i >> 4;
    const int oc = i & 15;
    wlds[i] = wt[oc * 81 + tap];
  }
  __syncthreads();

  const int w = tid & 127;
  const int g = tid >> 7;          // dz-group: 0 -> dz 0..10, 1 -> dz 11..21
  const int h = blockIdx.y;
  const int b = blockIdx.z;
  const bool active = (w < WOUT);
  const int wc = active ? w : 0;   // clamp inactive lanes to safe addresses

  // Slice base pointers for each (c, kd): depth index = g*DZH + kd
  const float* xb = x + (((size_t)b * CC * DD) * HH + h) * (size_t)WW + wc;
  const float* p0 = xb + (size_t)(0 * DD + g * DZH + 0) * HW;
  const float* p1 = xb + (size_t)(0 * DD + g * DZH + 1) * HW;
  const float* p2 = xb + (size_t)(0 * DD + g * DZH + 2) * HW;
  const float* p3 = xb + (size_t)(1 * DD + g * DZH + 0) * HW;
  const float* p4 = xb + (size_t)(1 * DD + g * DZH + 1) * HW;
  const float* p5 = xb + (size_t)(1 * DD + g * DZH + 2) * HW;
  const float* p6 = xb + (size_t)(2 * DD + g * DZH + 0) * HW;
  const float* p7 = xb + (size_t)(2 * DD + g * DZH + 1) * HW;
  const float* p8 = xb + (size_t)(2 * DD + g * DZH + 2) * HW;

  float m0 = INFINITY, m1 = INFINITY, m2 = INFINITY, m3 = INFINITY;
  float m4 = INFINITY, m5 = INFINITY, m6 = INFINITY, m7 = INFINITY;
  float m8 = INFINITY, m9 = INFINITY, m10 = INFINITY, m11 = INFINITY;
  float m12 = INFINITY, m13 = INFINITY, m14 = INFINITY, m15 = INFINITY;

  for (int i = 0; i < DZH; ++i) {
    float y0 = 0.f, y1 = 0.f, y2 = 0.f, y3 = 0.f;
    float y4 = 0.f, y5 = 0.f, y6 = 0.f, y7 = 0.f;
    float y8 = 0.f, y9 = 0.f, y10 = 0.f, y11 = 0.f;
    float y12 = 0.f, y13 = 0.f, y14 = 0.f, y15 = 0.f;

    SLICE(0, p0); SLICE(1, p1); SLICE(2, p2);
    SLICE(3, p3); SLICE(4, p4); SLICE(5, p5);
    SLICE(6, p6); SLICE(7, p7); SLICE(8, p8);

    m0 = fminf(m0, y0);   m1 = fminf(m1, y1);
    m2 = fminf(m2, y2);   m3 = fminf(m3, y3);
    m4 = fminf(m4, y4);   m5 = fminf(m5, y5);
    m6 = fminf(m6, y6);   m7 = fminf(m7, y7);
    m8 = fminf(m8, y8);   m9 = fminf(m9, y9);
    m10 = fminf(m10, y10); m11 = fminf(m11, y11);
    m12 = fminf(m12, y12); m13 = fminf(m13, y13);
    m14 = fminf(m14, y14); m15 = fminf(m15, y15);

    p0 += HW; p1 += HW; p2 += HW; p3 += HW; p4 += HW;
    p5 += HW; p6 += HW; p7 += HW; p8 += HW;
  }

  // Group 1 publishes its per-channel mins; group 0 combines + softmax + store.
  if (g == 1 && active) {
    float* s = &sm[w * 17];
    s[0] = m0;   s[1] = m1;   s[2] = m2;   s[3] = m3;
    s[4] = m4;   s[5] = m5;   s[6] = m6;   s[7] = m7;
    s[8] = m8;   s[9] = m9;   s[10] = m10; s[11] = m11;
    s[12] = m12; s[13] = m13; s[14] = m14; s[15] = m15;
  }
  __syncthreads();

  if (g == 0 && active) {
    const float* s = &sm[w * 17];
    m0 = fminf(m0, s[0]);   m1 = fminf(m1, s[1]);
    m2 = fminf(m2, s[2]);   m3 = fminf(m3, s[3]);
    m4 = fminf(m4, s[4]);   m5 = fminf(m5, s[5]);
    m6 = fminf(m6, s[6]);   m7 = fminf(m7, s[7]);
    m8 = fminf(m8, s[8]);   m9 = fminf(m9, s[9]);
    m10 = fminf(m10, s[10]); m11 = fminf(m11, s[11]);
    m12 = fminf(m12, s[12]); m13 = fminf(m13, s[13]);
    m14 = fminf(m14, s[14]); m15 = fminf(m15, s[15]);

    float mx = fmaxf(fmaxf(fmaxf(m0, m1), fmaxf(m2, m3)),
                     fmaxf(fmaxf(m4, m5), fmaxf(m6, m7)));
    mx = fmaxf(mx, fmaxf(fmaxf(fmaxf(m8, m9), fmaxf(m10, m11)),
                         fmaxf(fmaxf(m12, m13), fmaxf(m14, m15))));

    const float e0 = __expf(m0 - mx);   const float e1 = __expf(m1 - mx);
    const float e2 = __expf(m2 - mx);   const float e3 = __expf(m3 - mx);
    const float e4 = __expf(m4 - mx);   const float e5 = __expf(m5 - mx);
    const float e6 = __expf(m6 - mx);   const float e7 = __expf(m7 - mx);
    const float e8 = __expf(m8 - mx);   const float e9 = __expf(m9 - mx);
    const float e10 = __expf(m10 - mx); const float e11 = __expf(m11 - mx);
    const float e12 = __expf(m12 - mx); const float e13 = __expf(m13 - mx);
    const float e14 = __expf(m14 - mx); const float e15 = __expf(m15 - mx);

    const float sum = ((e0 + e1) + (e2 + e3)) + ((e4 + e5) + (e6 + e7)) +
                      ((e8 + e9) + (e10 + e11)) + ((e12 + e13) + (e14 + e15));
    const float inv = 1.f / sum;

    float* ob = out + (((size_t)b * OCC) * HOUT + h) * (size_t)WOUT + w;
    const size_t os = (size_t)HOUT * WOUT;
    ob[0 * os] = e0 * inv;   ob[1 * os] = e1 * inv;
    ob[2 * os] = e2 * inv;   ob[3 * os] = e3 * inv;
    ob[4 * os] = e4 * inv;   ob[5 * os] = e5 * inv;
    ob[6 * os] = e6 * inv;   ob[7 * os] = e7 * inv;
    ob[8 * os] = e8 * inv;   ob[9 * os] = e9 * inv;
    ob[10 * os] = e10 * inv; ob[11 * os] = e11 * inv;
    ob[12 * os] = e12 * inv; ob[13 * os] = e13 * inv;
    ob[14 * os] = e14 * inv; ob[15 * os] = e15 * inv;
  }
}

extern "C" void kernel_launch(void* const* d_in, const int* in_sizes, int n_in,
                              void* d_out, int out_size, void* d_ws, size_t ws_size,
                              hipStream_t stream) {
  const float* x = (const float*)d_in[0];
  const float* wt = (const float*)d_in[1];
  float* out = (float*)d_out;

  dim3 grid(1, HOUT, BB);   // 126 * 8 = 1008 blocks
  dim3 block(256, 1, 1);    // 4 waves: 2 dz-groups x 128 lanes (126 active)
  conv_min_softmax_kernel<<<grid, block, 0, stream>>>(x, wt, out);
}

// Round 4
// 105.749 us; speedup vs baseline: 29.5621x; 29.5621x over previous
//
#include <hip/hip_runtime.h>
#include <math.h>

// Problem constants
#define BB 8
#define CC 3
#define DD 24
#define HH 128
#define WW 128
#define HW (HH * WW)
#define OCC 16
#define DOUT 22   // 24 - 2
#define HOUT 126
#define WOUT 126
#define DZH 11    // dz per group (2 groups per block)

// Each 128-thread block: 2 waves. Wave g handles dz in [g*11, g*11+11).
// Each lane computes 2 adjacent output columns (w0 = 2*lane, w0+1) for all
// 16 channels. Weights live transposed in LDS ([tap][oc]) and are read as
// wave-uniform float4 broadcasts. The 9-slice (c,kd) loop is a RUNTIME loop
// so the compiler cannot hoist all 1296 weights and spill (rounds 2/3 bug).
__global__ __launch_bounds__(128) void conv_min_softmax_kernel(
    const float* __restrict__ x, const float* __restrict__ wt,
    float* __restrict__ out) {
  __shared__ __align__(16) float wlds[81 * 16];   // [tap][oc], 5184 B
  __shared__ __align__(16) float sm[WOUT * 16];   // group-1 partial mins [w][oc]

  const int tid = threadIdx.x;

  // Stage weights transposed: wlds[tap*16 + oc] = wt[oc*81 + tap]
  for (int i = tid; i < 81 * 16; i += 128) {
    wlds[i] = wt[(i & 15) * 81 + (i >> 4)];
  }
  __syncthreads();

  const int lane = tid & 63;
  const int g = tid >> 6;                 // dz-group: 0 or 1
  const int h = blockIdx.y;
  const int b = blockIdx.z;
  const bool active = (lane < 63);        // 63 lanes cover w0 = 0..124
  const int w0 = active ? (2 * lane) : 0; // clamp inactive lane's addresses

  // Pointer at (b, c=0, depth = g*DZH, h, w0)
  const float* xd = x + (((size_t)b * CC * DD + g * DZH) * HH + h) * (size_t)WW + w0;

  float mn0[OCC], mn1[OCC];
#pragma unroll
  for (int oc = 0; oc < OCC; ++oc) { mn0[oc] = INFINITY; mn1[oc] = INFINITY; }

#pragma clang loop unroll(disable)
  for (int i = 0; i < DZH; ++i) {
    float y0[OCC], y1[OCC];
#pragma unroll
    for (int oc = 0; oc < OCC; ++oc) { y0[oc] = 0.f; y1[oc] = 0.f; }

    const float* ps = xd;  // slice (c=0, kd=0)
#pragma clang loop unroll(disable)
    for (int s = 0; s < 9; ++s) {
      // 3 rows x 4 columns of x (covers both output columns' 3-wide windows)
      float xr[3][4];
#pragma unroll
      for (int kh = 0; kh < 3; ++kh) {
        const float2 a = *reinterpret_cast<const float2*>(ps + kh * WW);
        const float2 c2 = *reinterpret_cast<const float2*>(ps + kh * WW + 2);
        xr[kh][0] = a.x; xr[kh][1] = a.y; xr[kh][2] = c2.x; xr[kh][3] = c2.y;
      }
      const float* wp = &wlds[s * 144];  // 9 taps * 16 oc for this slice
#pragma unroll
      for (int kh = 0; kh < 3; ++kh) {
#pragma unroll
        for (int kw = 0; kw < 3; ++kw) {
          const float4 wA = *reinterpret_cast<const float4*>(wp + (kh * 3 + kw) * 16 + 0);
          const float4 wB = *reinterpret_cast<const float4*>(wp + (kh * 3 + kw) * 16 + 4);
          const float4 wC = *reinterpret_cast<const float4*>(wp + (kh * 3 + kw) * 16 + 8);
          const float4 wD = *reinterpret_cast<const float4*>(wp + (kh * 3 + kw) * 16 + 12);
          const float xa = xr[kh][kw];
          const float xb2 = xr[kh][kw + 1];
          y0[0]  = fmaf(xa, wA.x, y0[0]);   y1[0]  = fmaf(xb2, wA.x, y1[0]);
          y0[1]  = fmaf(xa, wA.y, y0[1]);   y1[1]  = fmaf(xb2, wA.y, y1[1]);
          y0[2]  = fmaf(xa, wA.z, y0[2]);   y1[2]  = fmaf(xb2, wA.z, y1[2]);
          y0[3]  = fmaf(xa, wA.w, y0[3]);   y1[3]  = fmaf(xb2, wA.w, y1[3]);
          y0[4]  = fmaf(xa, wB.x, y0[4]);   y1[4]  = fmaf(xb2, wB.x, y1[4]);
          y0[5]  = fmaf(xa, wB.y, y0[5]);   y1[5]  = fmaf(xb2, wB.y, y1[5]);
          y0[6]  = fmaf(xa, wB.z, y0[6]);   y1[6]  = fmaf(xb2, wB.z, y1[6]);
          y0[7]  = fmaf(xa, wB.w, y0[7]);   y1[7]  = fmaf(xb2, wB.w, y1[7]);
          y0[8]  = fmaf(xa, wC.x, y0[8]);   y1[8]  = fmaf(xb2, wC.x, y1[8]);
          y0[9]  = fmaf(xa, wC.y, y0[9]);   y1[9]  = fmaf(xb2, wC.y, y1[9]);
          y0[10] = fmaf(xa, wC.z, y0[10]);  y1[10] = fmaf(xb2, wC.z, y1[10]);
          y0[11] = fmaf(xa, wC.w, y0[11]);  y1[11] = fmaf(xb2, wC.w, y1[11]);
          y0[12] = fmaf(xa, wD.x, y0[12]);  y1[12] = fmaf(xb2, wD.x, y1[12]);
          y0[13] = fmaf(xa, wD.y, y0[13]);  y1[13] = fmaf(xb2, wD.y, y1[13]);
          y0[14] = fmaf(xa, wD.z, y0[14]);  y1[14] = fmaf(xb2, wD.z, y1[14]);
          y0[15] = fmaf(xa, wD.w, y0[15]);  y1[15] = fmaf(xb2, wD.w, y1[15]);
        }
      }
      // advance slice pointer: kd step = HW; (c,2)->(c+1,0) step = (DD-2)*HW
      ps += (s == 2 || s == 5) ? (size_t)(DD - 2) * HW : (size_t)HW;
    }

#pragma unroll
    for (int oc = 0; oc < OCC; ++oc) {
      mn0[oc] = fminf(mn0[oc], y0[oc]);
      mn1[oc] = fminf(mn1[oc], y1[oc]);
    }
    xd += HW;  // next depth
  }

  // Group 1 publishes partial mins; group 0 combines + softmax + stores.
  if (g == 1 && active) {
#pragma unroll
    for (int q = 0; q < 4; ++q) {
      float4 v0, v1;
      v0.x = mn0[q * 4 + 0]; v0.y = mn0[q * 4 + 1];
      v0.z = mn0[q * 4 + 2]; v0.w = mn0[q * 4 + 3];
      v1.x = mn1[q * 4 + 0]; v1.y = mn1[q * 4 + 1];
      v1.z = mn1[q * 4 + 2]; v1.w = mn1[q * 4 + 3];
      *reinterpret_cast<float4*>(&sm[(size_t)w0 * 16 + q * 4]) = v0;
      *reinterpret_cast<float4*>(&sm[(size_t)(w0 + 1) * 16 + q * 4]) = v1;
    }
  }
  __syncthreads();

  if (g == 0 && active) {
#pragma unroll
    for (int oc = 0; oc < OCC; ++oc) {
      mn0[oc] = fminf(mn0[oc], sm[(size_t)w0 * 16 + oc]);
      mn1[oc] = fminf(mn1[oc], sm[(size_t)(w0 + 1) * 16 + oc]);
    }
    float mx0 = mn0[0], mx1 = mn1[0];
#pragma unroll
    for (int oc = 1; oc < OCC; ++oc) {
      mx0 = fmaxf(mx0, mn0[oc]);
      mx1 = fmaxf(mx1, mn1[oc]);
    }
    float e0[OCC], e1[OCC];
    float s0 = 0.f, s1 = 0.f;
#pragma unroll
    for (int oc = 0; oc < OCC; ++oc) {
      e0[oc] = __expf(mn0[oc] - mx0); s0 += e0[oc];
      e1[oc] = __expf(mn1[oc] - mx1); s1 += e1[oc];
    }
    const float i0 = 1.f / s0;
    const float i1 = 1.f / s1;

    float* ob = out + ((size_t)b * OCC * HOUT + h) * (size_t)WOUT + w0;
    const size_t os = (size_t)HOUT * WOUT;
#pragma unroll
    for (int oc = 0; oc < OCC; ++oc) {
      float2 v;
      v.x = e0[oc] * i0;
      v.y = e1[oc] * i1;
      *reinterpret_cast<float2*>(ob + oc * os) = v;  // w0 even -> 8B aligned
    }
  }
}

extern "C" void kernel_launch(void* const* d_in, const int* in_sizes, int n_in,
                              void* d_out, int out_size, void* d_ws, size_t ws_size,
                              hipStream_t stream) {
  const float* x = (const float*)d_in[0];
  const float* wt = (const float*)d_in[1];
  float* out = (float*)d_out;

  dim3 grid(1, HOUT, BB);   // 1008 blocks
  dim3 block(128, 1, 1);    // 2 waves: dz-groups 0..10 / 11..21, Wtile=2
  conv_min_softmax_kernel<<<grid, block, 0, stream>>>(x, wt, out);
}

// Round 5
// 100.228 us; speedup vs baseline: 31.1907x; 1.0551x over previous
//
#include <hip/hip_runtime.h>
#include <math.h>

// Problem constants
#define BB 8
#define CC 3
#define DD 24
#define HH 128
#define WW 128
#define HW (HH * WW)
#define OCC 16
#define DOUT 22   // 24 - 2
#define HOUT 126
#define WOUT 126

// Kernel 1: transpose weights [oc][tap] -> [tap][oc] into d_ws so each tap's
// 16 oc-weights are contiguous (64 B) -> wave-uniform float4 loads become
// s_load_dwordx4 and weights live in SGPRs (v_fmac_f32 takes 1 SGPR operand).
__global__ void wtrans_kernel(const float* __restrict__ wt,
                              float* __restrict__ wT) {
  const int i = blockIdx.x * 256 + threadIdx.x;
  if (i < 81 * 16) {
    const int tap = i >> 4;
    const int oc = i & 15;
    wT[i] = wt[oc * 81 + tap];
  }
}

// Kernel 2: 256-thread blocks = 4 waves; wave g handles a dz sub-range
// ({5,6,6,5} of the 22 depths). Each lane computes 2 adjacent output columns
// (w0 = 2*lane) for all 16 channels. Weights are read from the transposed
// global copy at wave-uniform addresses in 3-tap (48-float) groups -> SGPRs,
// zero DS traffic in the main loop. Partial mins combined via LDS [oc][w]
// (2-way bank aliasing = free), softmax + stores by wave 0.
__global__ __launch_bounds__(256) void conv_min_softmax_kernel(
    const float* __restrict__ x, const float* __restrict__ wT,
    float* __restrict__ out) {
  __shared__ float sm[3][OCC][WOUT];  // waves 1..3 publish partial mins

  const int tid = threadIdx.x;
  const int lane = tid & 63;
  const int g = tid >> 6;  // wave id 0..3
  const int h = blockIdx.y;
  const int b = blockIdx.z;
  const bool active = (lane < 63);          // 63 lanes cover w0 = 0..124
  const int w0 = 2 * (active ? lane : 62);  // clamp inactive lane's addresses

  // dz ranges per wave: starts {0,5,11,17}, counts {5,6,6,5}
  const int dz0 = (g == 0) ? 0 : (g == 1) ? 5 : (g == 2) ? 11 : 17;
  const int ndz = (g == 1 || g == 2) ? 6 : 5;

  // Pointer at (b, c=0, depth=dz0, h, w0)
  const float* xd =
      x + (((size_t)b * CC * DD + dz0) * HH + h) * (size_t)WW + w0;

  float mn0[OCC], mn1[OCC];
#pragma unroll
  for (int oc = 0; oc < OCC; ++oc) { mn0[oc] = INFINITY; mn1[oc] = INFINITY; }

#pragma clang loop unroll(disable)
  for (int i = 0; i < ndz; ++i) {
    float y0[OCC], y1[OCC];
#pragma unroll
    for (int oc = 0; oc < OCC; ++oc) { y0[oc] = 0.f; y1[oc] = 0.f; }

    const float* ps = xd;  // slice (c=0, kd=0)
#pragma clang loop unroll(disable)
    for (int s = 0; s < 9; ++s) {  // slice = (c, kd)
      const float* wslice = wT + s * 144;
#pragma clang loop unroll(disable)
      for (int tg = 0; tg < 3; ++tg) {  // tg = kh row; 3 taps, 48 weights
        // 4 x-values of this input row (covers both output columns, kw 0..2)
        const float* row = ps + tg * WW;
        const float2 a = *reinterpret_cast<const float2*>(row);
        const float2 c2 = *reinterpret_cast<const float2*>(row + 2);
        const float xq0 = a.x, xq1 = a.y, xq2 = c2.x, xq3 = c2.y;

        const float* wp = wslice + tg * 48;
#pragma unroll
        for (int kw = 0; kw < 3; ++kw) {
          const float4 wA = *reinterpret_cast<const float4*>(wp + kw * 16 + 0);
          const float4 wB = *reinterpret_cast<const float4*>(wp + kw * 16 + 4);
          const float4 wC = *reinterpret_cast<const float4*>(wp + kw * 16 + 8);
          const float4 wD = *reinterpret_cast<const float4*>(wp + kw * 16 + 12);
          const float xa = (kw == 0) ? xq0 : (kw == 1) ? xq1 : xq2;
          const float xb2 = (kw == 0) ? xq1 : (kw == 1) ? xq2 : xq3;
          y0[0]  = fmaf(xa, wA.x, y0[0]);   y1[0]  = fmaf(xb2, wA.x, y1[0]);
          y0[1]  = fmaf(xa, wA.y, y0[1]);   y1[1]  = fmaf(xb2, wA.y, y1[1]);
          y0[2]  = fmaf(xa, wA.z, y0[2]);   y1[2]  = fmaf(xb2, wA.z, y1[2]);
          y0[3]  = fmaf(xa, wA.w, y0[3]);   y1[3]  = fmaf(xb2, wA.w, y1[3]);
          y0[4]  = fmaf(xa, wB.x, y0[4]);   y1[4]  = fmaf(xb2, wB.x, y1[4]);
          y0[5]  = fmaf(xa, wB.y, y0[5]);   y1[5]  = fmaf(xb2, wB.y, y1[5]);
          y0[6]  = fmaf(xa, wB.z, y0[6]);   y1[6]  = fmaf(xb2, wB.z, y1[6]);
          y0[7]  = fmaf(xa, wB.w, y0[7]);   y1[7]  = fmaf(xb2, wB.w, y1[7]);
          y0[8]  = fmaf(xa, wC.x, y0[8]);   y1[8]  = fmaf(xb2, wC.x, y1[8]);
          y0[9]  = fmaf(xa, wC.y, y0[9]);   y1[9]  = fmaf(xb2, wC.y, y1[9]);
          y0[10] = fmaf(xa, wC.z, y0[10]);  y1[10] = fmaf(xb2, wC.z, y1[10]);
          y0[11] = fmaf(xa, wC.w, y0[11]);  y1[11] = fmaf(xb2, wC.w, y1[11]);
          y0[12] = fmaf(xa, wD.x, y0[12]);  y1[12] = fmaf(xb2, wD.x, y1[12]);
          y0[13] = fmaf(xa, wD.y, y0[13]);  y1[13] = fmaf(xb2, wD.y, y1[13]);
          y0[14] = fmaf(xa, wD.z, y0[14]);  y1[14] = fmaf(xb2, wD.z, y1[14]);
          y0[15] = fmaf(xa, wD.w, y0[15]);  y1[15] = fmaf(xb2, wD.w, y1[15]);
        }
      }
      // advance slice: kd step = HW; (c,2)->(c+1,0) step = (DD-2)*HW
      ps += (s == 2 || s == 5) ? (size_t)(DD - 2) * HW : (size_t)HW;
    }

#pragma unroll
    for (int oc = 0; oc < OCC; ++oc) {
      mn0[oc] = fminf(mn0[oc], y0[oc]);
      mn1[oc] = fminf(mn1[oc], y1[oc]);
    }
    xd += HW;  // next depth
  }

  // Waves 1..3 publish per-channel partial mins (layout [oc][w]: lanes at
  // w0=2*lane -> 2-way bank aliasing, free).
  if (g > 0 && active) {
#pragma unroll
    for (int oc = 0; oc < OCC; ++oc) {
      sm[g - 1][oc][w0] = mn0[oc];
      sm[g - 1][oc][w0 + 1] = mn1[oc];
    }
  }
  __syncthreads();

  if (g == 0 && active) {
#pragma unroll
    for (int oc = 0; oc < OCC; ++oc) {
      mn0[oc] = fminf(fminf(mn0[oc], sm[0][oc][w0]),
                      fminf(sm[1][oc][w0], sm[2][oc][w0]));
      mn1[oc] = fminf(fminf(mn1[oc], sm[0][oc][w0 + 1]),
                      fminf(sm[1][oc][w0 + 1], sm[2][oc][w0 + 1]));
    }
    float mx0 = mn0[0], mx1 = mn1[0];
#pragma unroll
    for (int oc = 1; oc < OCC; ++oc) {
      mx0 = fmaxf(mx0, mn0[oc]);
      mx1 = fmaxf(mx1, mn1[oc]);
    }
    float e0[OCC], e1[OCC];
    float s0 = 0.f, s1 = 0.f;
#pragma unroll
    for (int oc = 0; oc < OCC; ++oc) {
      e0[oc] = __expf(mn0[oc] - mx0); s0 += e0[oc];
      e1[oc] = __expf(mn1[oc] - mx1); s1 += e1[oc];
    }
    const float i0 = 1.f / s0;
    const float i1 = 1.f / s1;

    float* ob = out + ((size_t)b * OCC * HOUT + h) * (size_t)WOUT + w0;
    const size_t os = (size_t)HOUT * WOUT;
#pragma unroll
    for (int oc = 0; oc < OCC; ++oc) {
      float2 v;
      v.x = e0[oc] * i0;
      v.y = e1[oc] * i1;
      *reinterpret_cast<float2*>(ob + oc * os) = v;  // w0 even -> 8B aligned
    }
  }
}

extern "C" void kernel_launch(void* const* d_in, const int* in_sizes, int n_in,
                              void* d_out, int out_size, void* d_ws, size_t ws_size,
                              hipStream_t stream) {
  const float* x = (const float*)d_in[0];
  const float* wt = (const float*)d_in[1];
  float* out = (float*)d_out;
  float* wT = (float*)d_ws;  // 81*16 floats = 5184 B scratch

  wtrans_kernel<<<dim3(6), dim3(256), 0, stream>>>(wt, wT);

  dim3 grid(1, HOUT, BB);   // 1008 blocks
  dim3 block(256, 1, 1);    // 4 waves = 4 dz-groups, Wtile=2
  conv_min_softmax_kernel<<<grid, block, 0, stream>>>(x, wT, out);
}